// Round 3
// baseline (516.682 us; speedup 1.0000x reference)
//
#include <hip/hip_runtime.h>
#include <hip/hip_bf16.h>
#include <cstddef>

// X=4096, H=1024, L=8, VT=512, ET=1024
// z = [input_x(4096) ; h_prev[l](1024) ; prev_layer(1024)] -> 6144 cols
// Wg: (L, 4H, 6144) row-major fp32. Gate order: i, f, o, s.

#define XDIM 4096
#define HDIM 1024
#define LNUM 8
#define ZDIM 6144
#define ZPAR 5120   // X + H (scan-independent prefix)
#define VT 512
#define ET 1024

__device__ __forceinline__ float sigmoidf_(float v) {
    return 1.0f / (1.0f + expf(-v));
}

// ---------------------------------------------------------------------------
// Zero the per-layer completion counters (graph-replay safe, handles ws poison)
// ---------------------------------------------------------------------------
__global__ void zero_cnt_kernel(int* __restrict__ cnt) {
    if (threadIdx.x < LNUM) cnt[threadIdx.x] = 0;
}

// ---------------------------------------------------------------------------
// Fused 8-layer scan: one persistent kernel, 1024 blocks x 256 threads.
// Block b owns h=b for every layer. Wave q computes gate row q*1024+b:
//   prefix dot over [x ; h_prev[l]] (5120 cols, scan-independent)
//   then carry dot over hidden[l-1] (1024 cols) after the layer-(l-1) flag.
// Layer sync: plain store -> __threadfence -> atomicAdd(cnt[l]); readers
// spin on acquire-load(cnt[l-1]) == 1024.
// Co-residency: LDS 24KB (6 blk/CU), __launch_bounds__(256,4) caps VGPR
// at 128 (>=4 blk/CU) -> all 1024 blocks resident; no deadlock.
// ---------------------------------------------------------------------------
__global__ __launch_bounds__(256, 4) void fused_scan_kernel(
    const float* __restrict__ x,
    const float* __restrict__ hprev,
    const float* __restrict__ Wg,
    const float* __restrict__ bg,
    const float* __restrict__ old_state,
    float* __restrict__ hidden,   // ws: L*H floats
    int* __restrict__ cnt)        // ws: L ints, zeroed per call
{
    __shared__ float z[ZPAR];     // 20 KB: [x ; hprev_l]
    __shared__ float hp[HDIM];    // 4 KB : hidden[l-1]
    __shared__ float gred[4];

    const int tid  = threadIdx.x;
    const int wave = tid >> 6;
    const int lane = tid & 63;
    const int h    = blockIdx.x;

    // stage x once (doesn't change across layers)
    for (int i = tid; i < XDIM / 4; i += 256)
        reinterpret_cast<float4*>(z)[i] = reinterpret_cast<const float4*>(x)[i];

    for (int l = 0; l < LNUM; ++l) {
        __syncthreads();  // protect z tail / hp / gred reuse (covers x-stage at l=0)

        // stage h_prev[l] into z[4096:5120] (256 thr x float4 = 1024 floats)
        reinterpret_cast<float4*>(z + XDIM)[tid] =
            reinterpret_cast<const float4*>(hprev + (size_t)l * HDIM)[tid];
        __syncthreads();

        const size_t row = (size_t)l * 4096 + (size_t)wave * HDIM + h;
        const float4* __restrict__ W4 =
            reinterpret_cast<const float4*>(Wg + row * ZDIM);
        const float4* __restrict__ z4 = reinterpret_cast<const float4*>(z);

        float acc = 0.0f;
        #pragma unroll 4
        for (int p = 0; p < 20; ++p) {          // 5120 floats = 1280 float4
            float4 w = W4[p * 64 + lane];
            float4 v = z4[p * 64 + lane];
            acc += w.x * v.x + w.y * v.y + w.z * v.z + w.w * v.w;
        }

        if (l > 0) {
            if (tid == 0) {
                while (__hip_atomic_load(&cnt[l - 1], __ATOMIC_ACQUIRE,
                                         __HIP_MEMORY_SCOPE_AGENT) < HDIM)
                    __builtin_amdgcn_s_sleep(1);
            }
            __syncthreads();
            // stage hidden[l-1]
            reinterpret_cast<float4*>(hp)[tid] =
                reinterpret_cast<const float4*>(hidden + (size_t)(l - 1) * HDIM)[tid];
            __syncthreads();

            const float4* __restrict__ C4 =
                reinterpret_cast<const float4*>(Wg + row * ZDIM + ZPAR);
            const float4* __restrict__ h4 = reinterpret_cast<const float4*>(hp);
            #pragma unroll
            for (int p = 0; p < 4; ++p) {       // 1024 floats = 256 float4
                float4 w = C4[p * 64 + lane];
                float4 v = h4[p * 64 + lane];
                acc += w.x * v.x + w.y * v.y + w.z * v.z + w.w * v.w;
            }
        }

        #pragma unroll
        for (int off = 32; off > 0; off >>= 1)
            acc += __shfl_down(acc, off, 64);
        if (lane == 0)
            gred[wave] = acc + bg[row];
        __syncthreads();

        if (tid == 0) {
            const float ig = sigmoidf_(gred[0]);
            const float fg = sigmoidf_(gred[1]);
            const float og = sigmoidf_(gred[2]);
            const float sg = tanhf(gred[3]);
            const float ns = fg * old_state[(size_t)l * HDIM + h] + ig * sg;
            hidden[(size_t)l * HDIM + h] = og * tanhf(ns);
            __threadfence();                 // device-scope release of hidden
            atomicAdd(&cnt[l], 1);           // device-scope signal
        }
    }
}

// ---------------------------------------------------------------------------
// Heads (unchanged from the passing R1 version): rows [0,512)->Wy, [512,1536)->We
// ---------------------------------------------------------------------------
__global__ __launch_bounds__(256) void head_kernel(
    const float* __restrict__ Wy, const float* __restrict__ by,
    const float* __restrict__ We, const float* __restrict__ be,
    const float* __restrict__ flat,
    float* __restrict__ out)
{
    __shared__ float z[LNUM * HDIM];  // 32 KB

    for (int i = threadIdx.x; i < (LNUM * HDIM) / 4; i += blockDim.x)
        reinterpret_cast<float4*>(z)[i] = reinterpret_cast<const float4*>(flat)[i];
    __syncthreads();

    const int wave = threadIdx.x >> 6;
    const int lane = threadIdx.x & 63;
    const int row  = blockIdx.x * 4 + wave;

    const float* __restrict__ W;
    float b;
    if (row < VT) { W = Wy + (size_t)row * (LNUM * HDIM);        b = by[row]; }
    else          { W = We + (size_t)(row - VT) * (LNUM * HDIM); b = be[row - VT]; }

    const float4* __restrict__ W4 = reinterpret_cast<const float4*>(W);
    const float4* __restrict__ z4 = reinterpret_cast<const float4*>(z);

    float acc = 0.0f;
    #pragma unroll 4
    for (int p = 0; p < 32; ++p) {               // 8192 floats = 2048 float4
        float4 w = W4[p * 64 + lane];
        float4 v = z4[p * 64 + lane];
        acc += w.x * v.x + w.y * v.y + w.z * v.z + w.w * v.w;
    }
    #pragma unroll
    for (int off = 32; off > 0; off >>= 1)
        acc += __shfl_down(acc, off, 64);

    if (lane == 0)
        out[row] = acc + b;
}

// ---------------------------------------------------------------------------
extern "C" void kernel_launch(void* const* d_in, const int* in_sizes, int n_in,
                              void* d_out, int out_size, void* d_ws, size_t ws_size,
                              hipStream_t stream)
{
    const float* x         = (const float*)d_in[0];
    const float* hprev     = (const float*)d_in[1];
    const float* Wg        = (const float*)d_in[2];
    const float* bg        = (const float*)d_in[3];
    const float* old_state = (const float*)d_in[4];
    const float* Wy        = (const float*)d_in[5];
    const float* by        = (const float*)d_in[6];
    const float* We        = (const float*)d_in[7];
    const float* be        = (const float*)d_in[8];
    float* out = (float*)d_out;

    float* hidden = (float*)d_ws;                 // L*H floats = 32 KB
    int*   cnt    = (int*)d_ws + LNUM * HDIM;     // L ints

    zero_cnt_kernel<<<1, 64, 0, stream>>>(cnt);

    fused_scan_kernel<<<1024, 256, 0, stream>>>(
        x, hprev, Wg, bg, old_state, hidden, cnt);

    head_kernel<<<(VT + ET) / 4, 256, 0, stream>>>(Wy, by, We, be, hidden, out);
}

// Round 4
// 170.468 us; speedup vs baseline: 3.0310x; 3.0310x over previous
//
#include <hip/hip_runtime.h>
#include <hip/hip_bf16.h>
#include <cstddef>

// X=4096, H=1024, L=8, VT=512, ET=1024
// z = [input_x(4096) ; h_prev[l](1024) ; prev_layer(1024)] -> 6144 cols
// Wg: (L, 4H, 6144) row-major fp32. Gate order: i, f, o, s.

#define XDIM 4096
#define HDIM 1024
#define LNUM 8
#define ZDIM 6144
#define ZPAR 5120   // X + H (scan-independent prefix)
#define VT 512
#define ET 1024

__device__ __forceinline__ float sigmoidf_(float v) {
    return 1.0f / (1.0f + expf(-v));
}

// ---------------------------------------------------------------------------
// Kernel P: prefix dots for ALL rows (5120 cols), + fused layer-0 LSTM cell.
// grid = 4096 blocks (8 layers x 512) x 256 threads.
// Block b: l = b>>9, h0 = (b&511)*2, h1 = h0+1.
// Wave w (= gate w) computes rows rA = l*4096 + w*1024 + h0 and rB = rA+1,
// sharing one LDS z-read per FMA pair (2 global streams/wave in flight).
// l==0: no carry exists (init hidden = 0) -> apply cell math here, write
//       hidden[0][h0..h1]. l>0: write partial[row] = dot + bg[row].
// ---------------------------------------------------------------------------
__global__ __launch_bounds__(256, 4) void prefix_kernel(
    const float* __restrict__ x,
    const float* __restrict__ hprev,
    const float* __restrict__ Wg,
    const float* __restrict__ bg,
    const float* __restrict__ old_state,
    float* __restrict__ partial,
    float* __restrict__ hidden)
{
    __shared__ float z[ZPAR];      // 20 KB
    __shared__ float g2[4][2];

    const int tid  = threadIdx.x;
    const int wave = tid >> 6;
    const int lane = tid & 63;
    const int l    = blockIdx.x >> 9;
    const int h0   = (blockIdx.x & 511) * 2;

    // stage z = [x ; h_prev[l]] (1280 float4, 5 per thread)
    for (int i = tid; i < XDIM / 4; i += 256)
        reinterpret_cast<float4*>(z)[i] = reinterpret_cast<const float4*>(x)[i];
    reinterpret_cast<float4*>(z + XDIM)[tid] =
        reinterpret_cast<const float4*>(hprev + (size_t)l * HDIM)[tid];
    __syncthreads();

    const size_t rA = (size_t)l * 4096 + (size_t)wave * HDIM + h0;
    const size_t rB = rA + 1;
    const float4* __restrict__ WA = reinterpret_cast<const float4*>(Wg + rA * ZDIM);
    const float4* __restrict__ WB = reinterpret_cast<const float4*>(Wg + rB * ZDIM);
    const float4* __restrict__ z4 = reinterpret_cast<const float4*>(z);

    float accA = 0.0f, accB = 0.0f;
    #pragma unroll 4
    for (int p = 0; p < 20; ++p) {              // 1280 float4 / 64 lanes
        const int idx = p * 64 + lane;
        float4 wa = WA[idx];
        float4 wb = WB[idx];
        float4 v  = z4[idx];
        accA += wa.x * v.x + wa.y * v.y + wa.z * v.z + wa.w * v.w;
        accB += wb.x * v.x + wb.y * v.y + wb.z * v.z + wb.w * v.w;
    }
    #pragma unroll
    for (int off = 32; off > 0; off >>= 1) {
        accA += __shfl_down(accA, off, 64);
        accB += __shfl_down(accB, off, 64);
    }

    if (l > 0) {
        if (lane == 0) {
            partial[rA] = accA + bg[rA];
            partial[rB] = accB + bg[rB];
        }
    } else {
        if (lane == 0) {
            g2[wave][0] = accA + bg[rA];
            g2[wave][1] = accB + bg[rB];
        }
        __syncthreads();
        if (tid == 0) {
            #pragma unroll
            for (int k = 0; k < 2; ++k) {
                const float ig = sigmoidf_(g2[0][k]);
                const float fg = sigmoidf_(g2[1][k]);
                const float og = sigmoidf_(g2[2][k]);
                const float sg = tanhf(g2[3][k]);
                const float ns = fg * old_state[h0 + k] + ig * sg;
                hidden[h0 + k] = og * tanhf(ns);
            }
        }
    }
}

// ---------------------------------------------------------------------------
// Kernel C (per layer l=1..7): carry dot (cols 5120:6144) + cell math.
// grid = 1024 blocks x 256: block = h, wave = gate q. 16.8 MB streamed.
// ---------------------------------------------------------------------------
__global__ __launch_bounds__(256) void carry_kernel(
    const float* __restrict__ Wg,
    const float* __restrict__ partial,
    const float* __restrict__ old_state,
    const float* __restrict__ hidden_prev,
    float* __restrict__ hidden_out,
    int l)
{
    __shared__ float hp[HDIM];     // 4 KB
    __shared__ float gred[4];

    const int tid  = threadIdx.x;
    const int wave = tid >> 6;
    const int lane = tid & 63;
    const int h    = blockIdx.x;

    reinterpret_cast<float4*>(hp)[tid] =
        reinterpret_cast<const float4*>(hidden_prev)[tid];
    __syncthreads();

    const size_t row = (size_t)l * 4096 + (size_t)wave * HDIM + h;
    const float4* __restrict__ W4 =
        reinterpret_cast<const float4*>(Wg + row * ZDIM + ZPAR);
    const float4* __restrict__ h4 = reinterpret_cast<const float4*>(hp);

    float acc = 0.0f;
    #pragma unroll
    for (int p = 0; p < 4; ++p) {               // 256 float4 / 64 lanes
        const int idx = p * 64 + lane;
        float4 w = W4[idx];
        float4 v = h4[idx];
        acc += w.x * v.x + w.y * v.y + w.z * v.z + w.w * v.w;
    }
    #pragma unroll
    for (int off = 32; off > 0; off >>= 1)
        acc += __shfl_down(acc, off, 64);
    if (lane == 0)
        gred[wave] = acc + partial[row];        // partial already includes bg
    __syncthreads();

    if (tid == 0) {
        const float ig = sigmoidf_(gred[0]);
        const float fg = sigmoidf_(gred[1]);
        const float og = sigmoidf_(gred[2]);
        const float sg = tanhf(gred[3]);
        const float ns = fg * old_state[(size_t)l * HDIM + h] + ig * sg;
        hidden_out[h] = og * tanhf(ns);
    }
}

// ---------------------------------------------------------------------------
// Kernel H: heads. One block per output row (1536 blocks x 256).
// flat (32 KB) is L2-hot broadcast -> read directly from global, no staging.
// Wave w covers quarter w of the 8192-dot; cross-wave reduce via 16B LDS.
// ---------------------------------------------------------------------------
__global__ __launch_bounds__(256) void head_kernel(
    const float* __restrict__ Wy, const float* __restrict__ by,
    const float* __restrict__ We, const float* __restrict__ be,
    const float* __restrict__ flat,
    float* __restrict__ out)
{
    __shared__ float gred[4];

    const int tid  = threadIdx.x;
    const int wave = tid >> 6;
    const int lane = tid & 63;
    const int r    = blockIdx.x;

    const float* __restrict__ W;
    float b;
    if (r < VT) { W = Wy + (size_t)r * (LNUM * HDIM);        b = by[r]; }
    else        { W = We + (size_t)(r - VT) * (LNUM * HDIM); b = be[r - VT]; }

    const float4* __restrict__ W4 = reinterpret_cast<const float4*>(W);
    const float4* __restrict__ f4 = reinterpret_cast<const float4*>(flat);

    float acc = 0.0f;
    #pragma unroll
    for (int j = 0; j < 8; ++j) {               // 2048 float4 / 4 waves / 64 lanes
        const int idx = wave * 512 + j * 64 + lane;
        float4 w = W4[idx];
        float4 v = f4[idx];
        acc += w.x * v.x + w.y * v.y + w.z * v.z + w.w * v.w;
    }
    #pragma unroll
    for (int off = 32; off > 0; off >>= 1)
        acc += __shfl_down(acc, off, 64);
    if (lane == 0) gred[wave] = acc;
    __syncthreads();

    if (tid == 0)
        out[r] = gred[0] + gred[1] + gred[2] + gred[3] + b;
}

// ---------------------------------------------------------------------------
extern "C" void kernel_launch(void* const* d_in, const int* in_sizes, int n_in,
                              void* d_out, int out_size, void* d_ws, size_t ws_size,
                              hipStream_t stream)
{
    const float* x         = (const float*)d_in[0];
    const float* hprev     = (const float*)d_in[1];
    const float* Wg        = (const float*)d_in[2];
    const float* bg        = (const float*)d_in[3];
    const float* old_state = (const float*)d_in[4];
    const float* Wy        = (const float*)d_in[5];
    const float* by        = (const float*)d_in[6];
    const float* We        = (const float*)d_in[7];
    const float* be        = (const float*)d_in[8];
    float* out = (float*)d_out;

    float* hidden  = (float*)d_ws;                 // L*H floats
    float* partial = hidden + LNUM * HDIM;         // L*4H floats

    // 1) prefix dots for all layers (+ fused layer-0 cell)
    prefix_kernel<<<4096, 256, 0, stream>>>(
        x, hprev, Wg, bg, old_state, partial, hidden);

    // 2) sequential carry chain, layers 1..7 (launch boundary = sync)
    for (int l = 1; l < LNUM; ++l) {
        carry_kernel<<<1024, 256, 0, stream>>>(
            Wg, partial, old_state,
            hidden + (size_t)(l - 1) * HDIM,
            hidden + (size_t)l * HDIM, l);
    }

    // 3) heads
    head_kernel<<<VT + ET, 256, 0, stream>>>(Wy, by, We, be, hidden, out);
}